// Round 3
// baseline (256.403 us; speedup 1.0000x reference)
//
#include <hip/hip_runtime.h>

#define STRINGS 6

// Each thread handles 4 consecutive rows of an [N][NC] f32 matrix (NC odd,
// so 4 rows = NC float4s, 16B-aligned at group base g*NC*16).
// Dual-matrix chunked argmax: load CH float4s from each matrix into explicit
// register arrays (forces batched issue, ~2*CH*4 VGPRs in flight), then
// compare with fully compile-time row/class decode.
template<int NC, int CH>
__device__ __forceinline__ void argmax_rows4_dual(
    const float* __restrict__ matA, const float* __restrict__ matB,
    int g, int idxA[4], int idxB[4])
{
    const float4* a = reinterpret_cast<const float4*>(matA) + (size_t)g * NC;
    const float4* b = reinterpret_cast<const float4*>(matB) + (size_t)g * NC;
    float bestA[4] = {-3.4e38f, -3.4e38f, -3.4e38f, -3.4e38f};
    float bestB[4] = {-3.4e38f, -3.4e38f, -3.4e38f, -3.4e38f};
    #pragma unroll
    for (int r = 0; r < 4; ++r) { idxA[r] = 0; idxB[r] = 0; }

    #pragma unroll
    for (int q0 = 0; q0 < NC; q0 += CH) {
        const int L = (NC - q0) < CH ? (NC - q0) : CH;   // compile-time
        float4 va[CH], vb[CH];
        #pragma unroll
        for (int i = 0; i < L; ++i) va[i] = a[q0 + i];
        #pragma unroll
        for (int i = 0; i < L; ++i) vb[i] = b[q0 + i];
        #pragma unroll
        for (int i = 0; i < L; ++i) {
            float xa[4] = {va[i].x, va[i].y, va[i].z, va[i].w};
            float xb[4] = {vb[i].x, vb[i].y, vb[i].z, vb[i].w};
            #pragma unroll
            for (int j = 0; j < 4; ++j) {
                const int e = (q0 + i) * 4 + j;   // compile-time
                const int r = e / NC;             // compile-time
                const int c = e - r * NC;         // compile-time
                if (xa[j] > bestA[r]) { bestA[r] = xa[j]; idxA[r] = c; }
                if (xb[j] > bestB[r]) { bestB[r] = xb[j]; idxB[r] = c; }
            }
        }
    }
}

// ws layout (u32): [0]=tabTP [1]=tabFP [2]=tabFN [3]=f0TP [4]=f0FP [5]=f0FN
__global__ __launch_bounds__(256, 2) void count_kernel(
    const float* __restrict__ tab_pred, const float* __restrict__ tab_gt,
    const float* __restrict__ f0_pred,  const float* __restrict__ f0_gt,
    const int* __restrict__ gtlen_p, unsigned int* __restrict__ ws,
    int tabBlocks, int tabGroups, int f0Groups)
{
    __shared__ unsigned int red[3];
    const int tid = threadIdx.x;
    if (tid < 3) red[tid] = 0;
    __syncthreads();

    const int gtlen = *gtlen_p;
    unsigned int tp = 0, fp = 0, fn = 0;
    int base;

    if (blockIdx.x < tabBlocks) {
        base = 0;
        const int g = blockIdx.x * 256 + tid;
        if (g < tabGroups) {
            int pidx[4], gidx[4];
            argmax_rows4_dual<21, 11>(tab_pred, tab_gt, g, pidx, gidx);
            #pragma unroll
            for (int k = 0; k < 4; ++k) {
                const int cell = g * 4 + k;
                const int t = cell / STRINGS;
                const bool predP = (t < gtlen) && (pidx[k] < 20);
                const bool gtP   = (gidx[k] < 20);
                const bool eq    = (pidx[k] == gidx[k]);
                tp += (predP && gtP && eq) ? 1u : 0u;
                fp += (predP && !(gtP && eq)) ? 1u : 0u;
                fn += (gtP && !(predP && eq)) ? 1u : 0u;
            }
        }
    } else {
        base = 3;
        const int g = (blockIdx.x - tabBlocks) * 256 + tid;
        if (g < f0Groups) {
            int pidx[4], gidx[4];
            argmax_rows4_dual<45, 15>(f0_pred, f0_gt, g, pidx, gidx);
            #pragma unroll
            for (int k = 0; k < 4; ++k) {
                const int t = g * 4 + k;
                const bool predP = (t < gtlen) && (pidx[k] < 44);
                const bool gtP   = (gidx[k] < 44);
                const bool eq    = (pidx[k] == gidx[k]);
                tp += (predP && gtP && eq) ? 1u : 0u;
                fp += (predP && !(gtP && eq)) ? 1u : 0u;
                fn += (gtP && !(predP && eq)) ? 1u : 0u;
            }
        }
    }

    atomicAdd(&red[0], tp);
    atomicAdd(&red[1], fp);
    atomicAdd(&red[2], fn);
    __syncthreads();
    if (tid == 0) {
        atomicAdd(&ws[base + 0], red[0]);
        atomicAdd(&ws[base + 1], red[1]);
        atomicAdd(&ws[base + 2], red[2]);
    }
}

__device__ __forceinline__ void write_scores(
    float TP, float TN, float FP, float FN, float* o)
{
    // matches jnp.nan_to_num(x/y): 0/0 -> 0
    float dp = TP + FP;
    float prec = (dp != 0.0f) ? TP / dp : 0.0f;
    float dr = TP + FN;
    float rec = (dr != 0.0f) ? TP / dr : 0.0f;
    float df = prec + rec;
    float f1 = (df != 0.0f) ? 2.0f * prec * rec / df : 0.0f;
    float acc = (TP + TN) / (TP + FN + TN + FP);
    o[0] = prec; o[1] = rec; o[2] = f1; o[3] = acc;
}

__global__ void score_kernel(const unsigned int* __restrict__ ws,
                             float* __restrict__ out,
                             unsigned long long tabTotal,
                             unsigned long long f0Total)
{
    if (blockIdx.x == 0 && threadIdx.x == 0) {
        unsigned long long ttp = ws[0], tfp = ws[1], tfn = ws[2];
        unsigned long long ftp = ws[3], ffp = ws[4], ffn = ws[5];
        unsigned long long ttn = tabTotal - ttp - tfp - tfn;
        unsigned long long ftn = f0Total - ftp - ffp - ffn;
        write_scores((float)ttp, (float)ttn, (float)tfp, (float)tfn, out);
        write_scores((float)ftp, (float)ftn, (float)ffp, (float)ffn, out + 4);
    }
}

extern "C" void kernel_launch(void* const* d_in, const int* in_sizes, int n_in,
                              void* d_out, int out_size, void* d_ws, size_t ws_size,
                              hipStream_t stream) {
    const float* tab_pred = (const float*)d_in[0];
    const float* F0_pred  = (const float*)d_in[1];
    const float* tab_gt   = (const float*)d_in[2];
    const float* F0_gt    = (const float*)d_in[3];
    const int*   gtlen    = (const int*)d_in[4];

    const int T = in_sizes[1] / 45;        // 500000
    const int ncells = T * STRINGS;        // 3,000,000 (divisible by 4)

    const int tabGroups = ncells / 4;      // 750000
    const int f0Groups  = T / 4;           // 125000
    const int tabBlocks = (tabGroups + 255) / 256;   // 2930
    const int f0Blocks  = (f0Groups + 255) / 256;    // 489

    unsigned int* ws = (unsigned int*)d_ws;
    hipMemsetAsync(d_ws, 0, 8 * sizeof(unsigned int), stream);

    count_kernel<<<tabBlocks + f0Blocks, 256, 0, stream>>>(
        tab_pred, tab_gt, F0_pred, F0_gt, gtlen, ws,
        tabBlocks, tabGroups, f0Groups);

    score_kernel<<<1, 1, 0, stream>>>(
        ws, (float*)d_out,
        (unsigned long long)ncells * 20,
        (unsigned long long)T * 44);
}